// Round 1
// baseline (1310.767 us; speedup 1.0000x reference)
//
#include <hip/hip_runtime.h>

#define N_NODES 131072
#define N_EDGES 2097152
#define N_GRAPHS 128

// ---------------- degrees ----------------
__global__ __launch_bounds__(256) void k_degrees(const int* __restrict__ src,
                                                 const int* __restrict__ dst,
                                                 int* __restrict__ outdeg,
                                                 int* __restrict__ indeg) {
  int e = blockIdx.x * 256 + threadIdx.x;
  atomicAdd(&outdeg[src[e]], 1);
  atomicAdd(&indeg[dst[e]], 1);
}

__global__ __launch_bounds__(256) void k_norms(const int* __restrict__ outdeg,
                                               const int* __restrict__ indeg,
                                               float* __restrict__ src_norm,
                                               float* __restrict__ dst_norm) {
  int n = blockIdx.x * 256 + threadIdx.x;
  int od = outdeg[n]; if (od < 1) od = 1;
  int id = indeg[n];  if (id < 1) id = 1;
  src_norm[n] = 1.0f / sqrtf((float)od);
  dst_norm[n] = 1.0f / sqrtf((float)id);
}

// ---------------- scan (exclusive prefix sum of indeg -> row_start) ----------------
__global__ __launch_bounds__(256) void k_scan_block(const int* __restrict__ indeg,
                                                    int* __restrict__ row_start,
                                                    int* __restrict__ partials) {
  __shared__ int tmp[256];
  int t = threadIdx.x;
  int n = blockIdx.x * 256 + t;
  int v = indeg[n];
  tmp[t] = v;
  __syncthreads();
  for (int off = 1; off < 256; off <<= 1) {
    int x = (t >= off) ? tmp[t - off] : 0;
    __syncthreads();
    tmp[t] += x;
    __syncthreads();
  }
  row_start[n] = tmp[t] - v;            // exclusive
  if (t == 255) partials[blockIdx.x] = tmp[t];
}

__global__ __launch_bounds__(512) void k_scan_partials(int* __restrict__ partials) {
  __shared__ int tmp[512];
  int t = threadIdx.x;
  int v = partials[t];
  tmp[t] = v;
  __syncthreads();
  for (int off = 1; off < 512; off <<= 1) {
    int x = (t >= off) ? tmp[t - off] : 0;
    __syncthreads();
    tmp[t] += x;
    __syncthreads();
  }
  partials[t] = tmp[t] - v;             // exclusive block offsets
}

__global__ __launch_bounds__(256) void k_scan_add(int* __restrict__ row_start,
                                                  const int* __restrict__ partials,
                                                  int* __restrict__ cursor) {
  int n = blockIdx.x * 256 + threadIdx.x;
  int v = row_start[n] + partials[blockIdx.x];
  row_start[n] = v;
  cursor[n] = v;
  if (n == 0) row_start[N_NODES] = N_EDGES;
}

__global__ __launch_bounds__(256) void k_fill(const int* __restrict__ dst,
                                              const int* __restrict__ src,
                                              int* __restrict__ cursor,
                                              int* __restrict__ csr_src) {
  int e = blockIdx.x * 256 + threadIdx.x;
  int d = dst[e];
  int p = atomicAdd(&cursor[d], 1);
  csr_src[p] = src[e];
}

// ---------------- GEMM: out[N,DOUT] = (h * src_norm) @ W ----------------
// 64-row tile, K-chunked LDS (transposed h tile, +4 pad for aligned b128 reads),
// 256 threads as 16(row-groups) x 16(col-groups), 4 x TN register tile.
template <int DIN, int DOUT>
__global__ __launch_bounds__(256) void k_gemm(const float* __restrict__ h,
                                              const float* __restrict__ src_norm,
                                              const float* __restrict__ W,
                                              float* __restrict__ out) {
  constexpr int KC   = (DIN < 64) ? DIN : 64;
  constexpr int ROWS = 64;
  constexpr int TN   = DOUT / 16;
  __shared__ float hT[KC][ROWS + 4];
  __shared__ float Ws[KC][DOUT];

  const int t = threadIdx.x;
  const int rowBase = blockIdx.x * ROWS;
  const int tr = t & 15;      // row group: rows tr*4 .. tr*4+3
  const int tc = t >> 4;      // col group: cols tc*TN .. tc*TN+TN-1

  float acc[4][TN];
#pragma unroll
  for (int i = 0; i < 4; ++i)
#pragma unroll
    for (int j = 0; j < TN; ++j) acc[i][j] = 0.0f;

  for (int kc = 0; kc < DIN; kc += KC) {
    // stage h tile (transposed, norm applied)
    constexpr int ELEMS = KC * ROWS;
#pragma unroll
    for (int base = 0; base < ELEMS; base += 256 * 4) {
      int idx = base + t * 4;
      if (idx < ELEMS) {
        int r  = idx / KC;
        int kk = idx % KC;
        float4 v = *reinterpret_cast<const float4*>(&h[(size_t)(rowBase + r) * DIN + kc + kk]);
        float nrm = src_norm[rowBase + r];
        hT[kk + 0][r] = v.x * nrm;
        hT[kk + 1][r] = v.y * nrm;
        hT[kk + 2][r] = v.z * nrm;
        hT[kk + 3][r] = v.w * nrm;
      }
    }
    // stage W chunk
    constexpr int WEL = KC * DOUT;
#pragma unroll
    for (int base = 0; base < WEL; base += 256 * 4) {
      int idx = base + t * 4;
      if (idx < WEL) {
        int kk = idx / DOUT;
        int c  = idx % DOUT;
        *reinterpret_cast<float4*>(&Ws[kk][c]) =
            *reinterpret_cast<const float4*>(&W[(size_t)(kc + kk) * DOUT + c]);
      }
    }
    __syncthreads();
#pragma unroll
    for (int kk = 0; kk < KC; ++kk) {
      float a[4], bb[TN];
#pragma unroll
      for (int i = 0; i < 4; ++i) a[i] = hT[kk][tr * 4 + i];
#pragma unroll
      for (int j = 0; j < TN; ++j) bb[j] = Ws[kk][tc * TN + j];
#pragma unroll
      for (int i = 0; i < 4; ++i)
#pragma unroll
        for (int j = 0; j < TN; ++j) acc[i][j] += a[i] * bb[j];
    }
    __syncthreads();
  }
#pragma unroll
  for (int i = 0; i < 4; ++i) {
    int row = rowBase + tr * 4 + i;
#pragma unroll
    for (int j = 0; j < TN; ++j)
      out[(size_t)row * DOUT + tc * TN + j] = acc[i][j];
  }
}

// ---------------- aggregation: out = relu(segment_sum(hw[csr]) * dst_norm + b) ----------------
template <int D>
__global__ __launch_bounds__(256) void k_agg(const float* __restrict__ hw,
                                             const int* __restrict__ row_start,
                                             const int* __restrict__ csr_src,
                                             const float* __restrict__ dst_norm,
                                             const float* __restrict__ bias,
                                             float* __restrict__ out) {
  constexpr int NPW = 64 / D;   // nodes per wave
  int t = threadIdx.x;
  int lane = t & 63;
  int wave = t >> 6;
  int f   = lane & (D - 1);
  int sub = lane / D;
  int node = (blockIdx.x * 4 + wave) * NPW + sub;
  if (node >= N_NODES) return;
  int start = row_start[node];
  int end   = row_start[node + 1];
  float acc = 0.0f;
  int i = start;
  for (; i + 4 <= end; i += 4) {
    int s0 = csr_src[i + 0];
    int s1 = csr_src[i + 1];
    int s2 = csr_src[i + 2];
    int s3 = csr_src[i + 3];
    float v0 = hw[(size_t)s0 * D + f];
    float v1 = hw[(size_t)s1 * D + f];
    float v2 = hw[(size_t)s2 * D + f];
    float v3 = hw[(size_t)s3 * D + f];
    acc += v0 + v1 + v2 + v3;
  }
  for (; i < end; ++i) acc += hw[(size_t)csr_src[i] * D + f];
  out[(size_t)node * D + f] = fmaxf(acc * dst_norm[node] + bias[f], 0.0f);
}

// ---------------- pooling + classifier ----------------
__global__ __launch_bounds__(256) void k_pool(const float* __restrict__ h3,
                                              const int* __restrict__ gid,
                                              float* __restrict__ sums,
                                              float* __restrict__ cnt) {
  int idx = blockIdx.x * 256 + threadIdx.x;   // N*16 threads
  int n = idx >> 4;
  int f = idx & 15;
  int g = gid[n];
  atomicAdd(&sums[g * 16 + f], h3[idx]);
  if (f == 0) atomicAdd(&cnt[g], 1.0f);
}

__global__ __launch_bounds__(128) void k_classify(const float* __restrict__ sums,
                                                  const float* __restrict__ cnt,
                                                  const float* __restrict__ Wc,
                                                  const float* __restrict__ bc,
                                                  float* __restrict__ out) {
  int g = threadIdx.x;
  float c = cnt[g]; if (c < 1.0f) c = 1.0f;
  float acc = 0.0f;
#pragma unroll
  for (int f = 0; f < 16; ++f) acc += (sums[g * 16 + f] / c) * Wc[f];
  out[g] = acc + bc[0];
}

// ---------------- launch ----------------
extern "C" void kernel_launch(void* const* d_in, const int* in_sizes, int n_in,
                              void* d_out, int out_size, void* d_ws, size_t ws_size,
                              hipStream_t stream) {
  const float* features = (const float*)d_in[0];
  const int*   src      = (const int*)d_in[1];
  const int*   dst      = (const int*)d_in[2];
  const int*   gid      = (const int*)d_in[3];
  const float* W0 = (const float*)d_in[4];
  const float* b0 = (const float*)d_in[5];
  const float* W1 = (const float*)d_in[6];
  const float* b1 = (const float*)d_in[7];
  const float* W2 = (const float*)d_in[8];
  const float* b2 = (const float*)d_in[9];
  const float* Wc = (const float*)d_in[10];
  const float* bc = (const float*)d_in[11];
  float* out = (float*)d_out;

  char* w = (char*)d_ws;
  auto alloc = [&](size_t bytes) {
    void* p = (void*)w;
    w += (bytes + 255) & ~(size_t)255;
    return p;
  };
  int*   outdeg    = (int*)alloc((size_t)N_NODES * 4);
  int*   indeg     = (int*)alloc((size_t)N_NODES * 4);
  float* src_norm  = (float*)alloc((size_t)N_NODES * 4);
  float* dst_norm  = (float*)alloc((size_t)N_NODES * 4);
  int*   row_start = (int*)alloc((size_t)(N_NODES + 1) * 4);
  int*   cursor    = (int*)alloc((size_t)N_NODES * 4);
  int*   partials  = (int*)alloc(512 * 4);
  int*   csr_src   = (int*)alloc((size_t)N_EDGES * 4);
  float* buf0      = (float*)alloc((size_t)N_NODES * 64 * 4);
  float* buf1      = (float*)alloc((size_t)N_NODES * 64 * 4);
  float* sums      = (float*)alloc((size_t)N_GRAPHS * 16 * 4);
  float* cnt       = (float*)alloc((size_t)N_GRAPHS * 4);

  // zero accumulators (outdeg+indeg contiguous; sums+cnt contiguous)
  hipMemsetAsync(outdeg, 0, (size_t)N_NODES * 2 * 4, stream);
  hipMemsetAsync(sums, 0, (size_t)(N_GRAPHS * 16 + N_GRAPHS) * 4, stream);

  k_degrees<<<N_EDGES / 256, 256, 0, stream>>>(src, dst, outdeg, indeg);
  k_norms<<<N_NODES / 256, 256, 0, stream>>>(outdeg, indeg, src_norm, dst_norm);
  k_scan_block<<<N_NODES / 256, 256, 0, stream>>>(indeg, row_start, partials);
  k_scan_partials<<<1, 512, 0, stream>>>(partials);
  k_scan_add<<<N_NODES / 256, 256, 0, stream>>>(row_start, partials, cursor);
  k_fill<<<N_EDGES / 256, 256, 0, stream>>>(dst, src, cursor, csr_src);

  // layer 0: 256 -> 64
  k_gemm<256, 64><<<N_NODES / 64, 256, 0, stream>>>(features, src_norm, W0, buf0);
  k_agg<64><<<N_NODES / 4, 256, 0, stream>>>(buf0, row_start, csr_src, dst_norm, b0, buf1);
  // layer 1: 64 -> 32
  k_gemm<64, 32><<<N_NODES / 64, 256, 0, stream>>>(buf1, src_norm, W1, buf0);
  k_agg<32><<<N_NODES / 8, 256, 0, stream>>>(buf0, row_start, csr_src, dst_norm, b1, buf1);
  // layer 2: 32 -> 16
  k_gemm<32, 16><<<N_NODES / 64, 256, 0, stream>>>(buf1, src_norm, W2, buf0);
  k_agg<16><<<N_NODES / 16, 256, 0, stream>>>(buf0, row_start, csr_src, dst_norm, b2, buf1);

  k_pool<<<(size_t)N_NODES * 16 / 256, 256, 0, stream>>>(buf1, gid, sums, cnt);
  k_classify<<<1, 128, 0, stream>>>(sums, cnt, Wc, bc, out);
}

// Round 3
// 659.983 us; speedup vs baseline: 1.9861x; 1.9861x over previous
//
#include <hip/hip_runtime.h>

#define N_NODES 131072
#define N_EDGES 2097152
#define N_GRAPHS 128
#define POOL_NPB 256   // nodes per block in k_pool

// ---------------- degrees ----------------
__global__ __launch_bounds__(256) void k_degrees(const int* __restrict__ src,
                                                 const int* __restrict__ dst,
                                                 int* __restrict__ outdeg,
                                                 int* __restrict__ indeg) {
  int e = blockIdx.x * 256 + threadIdx.x;
  atomicAdd(&outdeg[src[e]], 1);
  atomicAdd(&indeg[dst[e]], 1);
}

__global__ __launch_bounds__(256) void k_norms(const int* __restrict__ outdeg,
                                               const int* __restrict__ indeg,
                                               float* __restrict__ src_norm,
                                               float* __restrict__ dst_norm) {
  int n = blockIdx.x * 256 + threadIdx.x;
  int od = outdeg[n]; if (od < 1) od = 1;
  int id = indeg[n];  if (id < 1) id = 1;
  src_norm[n] = 1.0f / sqrtf((float)od);
  dst_norm[n] = 1.0f / sqrtf((float)id);
}

// ---------------- scan (exclusive prefix sum of indeg -> row_start) ----------------
__global__ __launch_bounds__(256) void k_scan_block(const int* __restrict__ indeg,
                                                    int* __restrict__ row_start,
                                                    int* __restrict__ partials) {
  __shared__ int tmp[256];
  int t = threadIdx.x;
  int n = blockIdx.x * 256 + t;
  int v = indeg[n];
  tmp[t] = v;
  __syncthreads();
  for (int off = 1; off < 256; off <<= 1) {
    int x = (t >= off) ? tmp[t - off] : 0;
    __syncthreads();
    tmp[t] += x;
    __syncthreads();
  }
  row_start[n] = tmp[t] - v;            // exclusive
  if (t == 255) partials[blockIdx.x] = tmp[t];
}

__global__ __launch_bounds__(512) void k_scan_partials(int* __restrict__ partials) {
  __shared__ int tmp[512];
  int t = threadIdx.x;
  int v = partials[t];
  tmp[t] = v;
  __syncthreads();
  for (int off = 1; off < 512; off <<= 1) {
    int x = (t >= off) ? tmp[t - off] : 0;
    __syncthreads();
    tmp[t] += x;
    __syncthreads();
  }
  partials[t] = tmp[t] - v;             // exclusive block offsets
}

__global__ __launch_bounds__(256) void k_scan_add(int* __restrict__ row_start,
                                                  const int* __restrict__ partials,
                                                  int* __restrict__ cursor) {
  int n = blockIdx.x * 256 + threadIdx.x;
  int v = row_start[n] + partials[blockIdx.x];
  row_start[n] = v;
  cursor[n] = v;
  if (n == 0) row_start[N_NODES] = N_EDGES;
}

__global__ __launch_bounds__(256) void k_fill(const int* __restrict__ dst,
                                              const int* __restrict__ src,
                                              int* __restrict__ cursor,
                                              int* __restrict__ csr_src) {
  int e = blockIdx.x * 256 + threadIdx.x;
  int d = dst[e];
  int p = atomicAdd(&cursor[d], 1);
  csr_src[p] = src[e];
}

// ---------------- GEMM: out[N,DOUT] = (h * src_norm) @ W ----------------
template <int DIN, int DOUT>
__global__ __launch_bounds__(256) void k_gemm(const float* __restrict__ h,
                                              const float* __restrict__ src_norm,
                                              const float* __restrict__ W,
                                              float* __restrict__ out) {
  constexpr int KC   = (DIN < 64) ? DIN : 64;
  constexpr int ROWS = 64;
  constexpr int TN   = DOUT / 16;
  __shared__ float hT[KC][ROWS + 4];
  __shared__ float Ws[KC][DOUT];

  const int t = threadIdx.x;
  const int rowBase = blockIdx.x * ROWS;
  const int tr = t & 15;      // row group: rows tr*4 .. tr*4+3
  const int tc = t >> 4;      // col group: cols tc*TN .. tc*TN+TN-1

  float acc[4][TN];
#pragma unroll
  for (int i = 0; i < 4; ++i)
#pragma unroll
    for (int j = 0; j < TN; ++j) acc[i][j] = 0.0f;

  for (int kc = 0; kc < DIN; kc += KC) {
    constexpr int ELEMS = KC * ROWS;
#pragma unroll
    for (int base = 0; base < ELEMS; base += 256 * 4) {
      int idx = base + t * 4;
      if (idx < ELEMS) {
        int r  = idx / KC;
        int kk = idx % KC;
        float4 v = *reinterpret_cast<const float4*>(&h[(size_t)(rowBase + r) * DIN + kc + kk]);
        float nrm = src_norm[rowBase + r];
        hT[kk + 0][r] = v.x * nrm;
        hT[kk + 1][r] = v.y * nrm;
        hT[kk + 2][r] = v.z * nrm;
        hT[kk + 3][r] = v.w * nrm;
      }
    }
    constexpr int WEL = KC * DOUT;
#pragma unroll
    for (int base = 0; base < WEL; base += 256 * 4) {
      int idx = base + t * 4;
      if (idx < WEL) {
        int kk = idx / DOUT;
        int c  = idx % DOUT;
        *reinterpret_cast<float4*>(&Ws[kk][c]) =
            *reinterpret_cast<const float4*>(&W[(size_t)(kc + kk) * DOUT + c]);
      }
    }
    __syncthreads();
#pragma unroll
    for (int kk = 0; kk < KC; ++kk) {
      float a[4], bb[TN];
#pragma unroll
      for (int i = 0; i < 4; ++i) a[i] = hT[kk][tr * 4 + i];
#pragma unroll
      for (int j = 0; j < TN; ++j) bb[j] = Ws[kk][tc * TN + j];
#pragma unroll
      for (int i = 0; i < 4; ++i)
#pragma unroll
        for (int j = 0; j < TN; ++j) acc[i][j] += a[i] * bb[j];
    }
    __syncthreads();
  }
#pragma unroll
  for (int i = 0; i < 4; ++i) {
    int row = rowBase + tr * 4 + i;
#pragma unroll
    for (int j = 0; j < TN; ++j)
      out[(size_t)row * DOUT + tc * TN + j] = acc[i][j];
  }
}

// ---------------- aggregation: out = relu(segment_sum(hw[csr]) * dst_norm + b) ----------------
template <int D>
__global__ __launch_bounds__(256) void k_agg(const float* __restrict__ hw,
                                             const int* __restrict__ row_start,
                                             const int* __restrict__ csr_src,
                                             const float* __restrict__ dst_norm,
                                             const float* __restrict__ bias,
                                             float* __restrict__ out) {
  constexpr int NPW = 64 / D;   // nodes per wave
  int t = threadIdx.x;
  int lane = t & 63;
  int wave = t >> 6;
  int f   = lane & (D - 1);
  int sub = lane / D;
  int node = (blockIdx.x * 4 + wave) * NPW + sub;
  if (node >= N_NODES) return;
  int start = row_start[node];
  int end   = row_start[node + 1];
  float acc = 0.0f;
  int i = start;
  for (; i + 4 <= end; i += 4) {
    int s0 = csr_src[i + 0];
    int s1 = csr_src[i + 1];
    int s2 = csr_src[i + 2];
    int s3 = csr_src[i + 3];
    float v0 = hw[(size_t)s0 * D + f];
    float v1 = hw[(size_t)s1 * D + f];
    float v2 = hw[(size_t)s2 * D + f];
    float v3 = hw[(size_t)s3 * D + f];
    acc += v0 + v1 + v2 + v3;
  }
  for (; i < end; ++i) acc += hw[(size_t)csr_src[i] * D + f];
  out[(size_t)node * D + f] = fmaxf(acc * dst_norm[node] + bias[f], 0.0f);
}

// ---------------- pooling: run-length local accumulate, flush atomic on gid change ----
// graph_ids is SORTED. Block owns POOL_NPB consecutive nodes: 16 lane-groups x
// 16 features; each thread walks POOL_NPB/16 nodes (stride 16), flushing one
// atomic per graph transition. Grid MUST be N_NODES / POOL_NPB.
__global__ __launch_bounds__(256) void k_pool(const float* __restrict__ h3,
                                              const int* __restrict__ gid,
                                              float* __restrict__ sums,
                                              float* __restrict__ cnt) {
  const int t = threadIdx.x;
  const int f = t & 15;
  const int grp = t >> 4;                 // 0..15
  const int base = blockIdx.x * POOL_NPB;
  float acc = 0.0f, c = 0.0f;
  int cur = gid[base + grp];
#pragma unroll 4
  for (int k = 0; k < POOL_NPB / 16; ++k) {
    int node = base + grp + k * 16;
    int g = gid[node];
    float v = h3[(size_t)node * 16 + f];
    if (g != cur) {
      atomicAdd(&sums[cur * 16 + f], acc);
      if (f == 0) atomicAdd(&cnt[cur], c);
      acc = 0.0f; c = 0.0f; cur = g;
    }
    acc += v; c += 1.0f;
  }
  atomicAdd(&sums[cur * 16 + f], acc);
  if (f == 0) atomicAdd(&cnt[cur], c);
}

__global__ __launch_bounds__(128) void k_classify(const float* __restrict__ sums,
                                                  const float* __restrict__ cnt,
                                                  const float* __restrict__ Wc,
                                                  const float* __restrict__ bc,
                                                  float* __restrict__ out) {
  int g = threadIdx.x;
  float c = cnt[g]; if (c < 1.0f) c = 1.0f;
  float acc = 0.0f;
#pragma unroll
  for (int f = 0; f < 16; ++f) acc += (sums[g * 16 + f] / c) * Wc[f];
  out[g] = acc + bc[0];
}

// ---------------- launch ----------------
extern "C" void kernel_launch(void* const* d_in, const int* in_sizes, int n_in,
                              void* d_out, int out_size, void* d_ws, size_t ws_size,
                              hipStream_t stream) {
  const float* features = (const float*)d_in[0];
  const int*   src      = (const int*)d_in[1];
  const int*   dst      = (const int*)d_in[2];
  const int*   gid      = (const int*)d_in[3];
  const float* W0 = (const float*)d_in[4];
  const float* b0 = (const float*)d_in[5];
  const float* W1 = (const float*)d_in[6];
  const float* b1 = (const float*)d_in[7];
  const float* W2 = (const float*)d_in[8];
  const float* b2 = (const float*)d_in[9];
  const float* Wc = (const float*)d_in[10];
  const float* bc = (const float*)d_in[11];
  float* out = (float*)d_out;

  char* w = (char*)d_ws;
  auto alloc = [&](size_t bytes) {
    void* p = (void*)w;
    w += (bytes + 255) & ~(size_t)255;
    return p;
  };
  int*   outdeg    = (int*)alloc((size_t)N_NODES * 4);
  int*   indeg     = (int*)alloc((size_t)N_NODES * 4);
  float* src_norm  = (float*)alloc((size_t)N_NODES * 4);
  float* dst_norm  = (float*)alloc((size_t)N_NODES * 4);
  int*   row_start = (int*)alloc((size_t)(N_NODES + 1) * 4);
  int*   cursor    = (int*)alloc((size_t)N_NODES * 4);
  int*   partials  = (int*)alloc(512 * 4);
  int*   csr_src   = (int*)alloc((size_t)N_EDGES * 4);
  float* buf0      = (float*)alloc((size_t)N_NODES * 64 * 4);
  float* buf1      = (float*)alloc((size_t)N_NODES * 64 * 4);
  float* sums      = (float*)alloc((size_t)N_GRAPHS * 16 * 4);
  float* cnt       = (float*)alloc((size_t)N_GRAPHS * 4);

  hipMemsetAsync(outdeg, 0, (size_t)N_NODES * 2 * 4, stream);
  hipMemsetAsync(sums, 0, (size_t)(N_GRAPHS * 16 + N_GRAPHS) * 4, stream);

  k_degrees<<<N_EDGES / 256, 256, 0, stream>>>(src, dst, outdeg, indeg);
  k_norms<<<N_NODES / 256, 256, 0, stream>>>(outdeg, indeg, src_norm, dst_norm);
  k_scan_block<<<N_NODES / 256, 256, 0, stream>>>(indeg, row_start, partials);
  k_scan_partials<<<1, 512, 0, stream>>>(partials);
  k_scan_add<<<N_NODES / 256, 256, 0, stream>>>(row_start, partials, cursor);
  k_fill<<<N_EDGES / 256, 256, 0, stream>>>(dst, src, cursor, csr_src);

  // layer 0: 256 -> 64
  k_gemm<256, 64><<<N_NODES / 64, 256, 0, stream>>>(features, src_norm, W0, buf0);
  k_agg<64><<<N_NODES / 4, 256, 0, stream>>>(buf0, row_start, csr_src, dst_norm, b0, buf1);
  // layer 1: 64 -> 32
  k_gemm<64, 32><<<N_NODES / 64, 256, 0, stream>>>(buf1, src_norm, W1, buf0);
  k_agg<32><<<N_NODES / 8, 256, 0, stream>>>(buf0, row_start, csr_src, dst_norm, b1, buf1);
  // layer 2: 32 -> 16
  k_gemm<32, 16><<<N_NODES / 64, 256, 0, stream>>>(buf1, src_norm, W2, buf0);
  k_agg<16><<<N_NODES / 16, 256, 0, stream>>>(buf0, row_start, csr_src, dst_norm, b2, buf1);

  k_pool<<<N_NODES / POOL_NPB, 256, 0, stream>>>(buf1, gid, sums, cnt);
  k_classify<<<1, 128, 0, stream>>>(sums, cnt, Wc, bc, out);
}

// Round 4
// 520.058 us; speedup vs baseline: 2.5204x; 1.2691x over previous
//
#include <hip/hip_runtime.h>

#define N_NODES 131072
#define N_EDGES 2097152
#define N_GRAPHS 128
#define POOL_NPB 256     // nodes per block in k_pool
#define NB 512           // CSR buckets (dst >> 8 -> 256 nodes per bucket)
#define BUCKET_CAP 5120  // max edges per bucket (mean 4096, +16 sigma)
#define BIN_EPB 16       // edges per thread in k_bin (4096 per block)

__global__ __launch_bounds__(256) void k_norms(const int* __restrict__ outdeg,
                                               const int* __restrict__ indeg,
                                               float* __restrict__ src_norm,
                                               float* __restrict__ dst_norm) {
  int n = blockIdx.x * 256 + threadIdx.x;
  int od = outdeg[n]; if (od < 1) od = 1;
  int id = indeg[n];  if (id < 1) id = 1;
  src_norm[n] = 1.0f / sqrtf((float)od);
  dst_norm[n] = 1.0f / sqrtf((float)id);
}

// ---------------- scan (exclusive prefix sum of indeg -> row_start) ----------------
__global__ __launch_bounds__(256) void k_scan_block(const int* __restrict__ indeg,
                                                    int* __restrict__ row_start,
                                                    int* __restrict__ partials) {
  __shared__ int tmp[256];
  int t = threadIdx.x;
  int n = blockIdx.x * 256 + t;
  int v = indeg[n];
  tmp[t] = v;
  __syncthreads();
  for (int off = 1; off < 256; off <<= 1) {
    int x = (t >= off) ? tmp[t - off] : 0;
    __syncthreads();
    tmp[t] += x;
    __syncthreads();
  }
  row_start[n] = tmp[t] - v;            // exclusive
  if (t == 255) partials[blockIdx.x] = tmp[t];
}

__global__ __launch_bounds__(512) void k_scan_partials(int* __restrict__ partials) {
  __shared__ int tmp[512];
  int t = threadIdx.x;
  int v = partials[t];
  tmp[t] = v;
  __syncthreads();
  for (int off = 1; off < 512; off <<= 1) {
    int x = (t >= off) ? tmp[t - off] : 0;
    __syncthreads();
    tmp[t] += x;
    __syncthreads();
  }
  partials[t] = tmp[t] - v;             // exclusive block offsets
}

__global__ __launch_bounds__(256) void k_scan_add(int* __restrict__ row_start,
                                                  const int* __restrict__ partials) {
  int n = blockIdx.x * 256 + threadIdx.x;
  row_start[n] += partials[blockIdx.x];
  if (n == 0) row_start[N_NODES] = N_EDGES;
}

// ---------------- bucket init ----------------
__global__ __launch_bounds__(256) void k_init_buckets(int* __restrict__ bucket_cursor) {
  int i = blockIdx.x * 256 + threadIdx.x;
  if (i < NB) bucket_cursor[i] = i * BUCKET_CAP;
}

// ---------------- phase A: bin edges by dst>>8, count degrees ----------------
// Per block: LDS histogram -> one chunk-reservation atomic per (block,bucket) ->
// grouped record writes (runs of ~8 x 8B per bucket -> full-line writebacks).
__global__ __launch_bounds__(256) void k_bin(const int* __restrict__ src,
                                             const int* __restrict__ dst,
                                             int* __restrict__ outdeg,
                                             int* __restrict__ indeg,
                                             int* __restrict__ bucket_cursor,
                                             int2* __restrict__ recs) {
  __shared__ int hist[NB];
  __shared__ int base[NB];
  const int t = threadIdx.x;
  const int e0 = blockIdx.x * (256 * BIN_EPB);
  for (int i = t; i < NB; i += 256) hist[i] = 0;
  __syncthreads();
  int myrank[BIN_EPB];
#pragma unroll
  for (int k = 0; k < BIN_EPB; ++k) {
    int e = e0 + k * 256 + t;
    int s = src[e];
    int d = dst[e];
    myrank[k] = atomicAdd(&hist[d >> 8], 1);
    atomicAdd(&outdeg[s], 1);
    atomicAdd(&indeg[d], 1);
  }
  __syncthreads();
  for (int i = t; i < NB; i += 256) {
    int c = hist[i];
    base[i] = c ? atomicAdd(&bucket_cursor[i], c) : 0;
  }
  __syncthreads();
#pragma unroll
  for (int k = 0; k < BIN_EPB; ++k) {
    int e = e0 + k * 256 + t;       // re-read (L1/L2 hot) to save VGPRs
    int s = src[e];
    int d = dst[e];
    recs[base[d >> 8] + myrank[k]] = make_int2(s, d);
  }
}

// ---------------- phase B: per-bucket CSR fill with LDS cursors ----------------
__global__ __launch_bounds__(256) void k_fill2(const int2* __restrict__ recs,
                                               const int* __restrict__ bucket_cursor,
                                               const int* __restrict__ row_start,
                                               int* __restrict__ csr_src) {
  __shared__ int lcur[256];
  const int b = blockIdx.x;
  const int t = threadIdx.x;
  lcur[t] = row_start[b * 256 + t];
  __syncthreads();
  const int beg = b * BUCKET_CAP;
  const int end = bucket_cursor[b];     // beg + count
  for (int i = beg + t; i < end; i += 256) {
    int2 r = recs[i];
    int p = atomicAdd(&lcur[r.y & 255], 1);
    csr_src[p] = r.x;
  }
}

// ---------------- GEMM: out[N,DOUT] = (h * src_norm) @ W ----------------
template <int DIN, int DOUT>
__global__ __launch_bounds__(256) void k_gemm(const float* __restrict__ h,
                                              const float* __restrict__ src_norm,
                                              const float* __restrict__ W,
                                              float* __restrict__ out) {
  constexpr int KC   = (DIN < 64) ? DIN : 64;
  constexpr int ROWS = 64;
  constexpr int TN   = DOUT / 16;
  __shared__ float hT[KC][ROWS + 4];
  __shared__ float Ws[KC][DOUT];

  const int t = threadIdx.x;
  const int rowBase = blockIdx.x * ROWS;
  const int tr = t & 15;
  const int tc = t >> 4;

  float acc[4][TN];
#pragma unroll
  for (int i = 0; i < 4; ++i)
#pragma unroll
    for (int j = 0; j < TN; ++j) acc[i][j] = 0.0f;

  for (int kc = 0; kc < DIN; kc += KC) {
    constexpr int ELEMS = KC * ROWS;
#pragma unroll
    for (int base = 0; base < ELEMS; base += 256 * 4) {
      int idx = base + t * 4;
      if (idx < ELEMS) {
        int r  = idx / KC;
        int kk = idx % KC;
        float4 v = *reinterpret_cast<const float4*>(&h[(size_t)(rowBase + r) * DIN + kc + kk]);
        float nrm = src_norm[rowBase + r];
        hT[kk + 0][r] = v.x * nrm;
        hT[kk + 1][r] = v.y * nrm;
        hT[kk + 2][r] = v.z * nrm;
        hT[kk + 3][r] = v.w * nrm;
      }
    }
    constexpr int WEL = KC * DOUT;
#pragma unroll
    for (int base = 0; base < WEL; base += 256 * 4) {
      int idx = base + t * 4;
      if (idx < WEL) {
        int kk = idx / DOUT;
        int c  = idx % DOUT;
        *reinterpret_cast<float4*>(&Ws[kk][c]) =
            *reinterpret_cast<const float4*>(&W[(size_t)(kc + kk) * DOUT + c]);
      }
    }
    __syncthreads();
#pragma unroll
    for (int kk = 0; kk < KC; ++kk) {
      float a[4], bb[TN];
#pragma unroll
      for (int i = 0; i < 4; ++i) a[i] = hT[kk][tr * 4 + i];
#pragma unroll
      for (int j = 0; j < TN; ++j) bb[j] = Ws[kk][tc * TN + j];
#pragma unroll
      for (int i = 0; i < 4; ++i)
#pragma unroll
        for (int j = 0; j < TN; ++j) acc[i][j] += a[i] * bb[j];
    }
    __syncthreads();
  }
#pragma unroll
  for (int i = 0; i < 4; ++i) {
    int row = rowBase + tr * 4 + i;
#pragma unroll
    for (int j = 0; j < TN; ++j)
      out[(size_t)row * DOUT + tc * TN + j] = acc[i][j];
  }
}

// ---------------- aggregation: out = relu(segment_sum(hw[csr]) * dst_norm + b) ----------------
template <int D>
__global__ __launch_bounds__(256) void k_agg(const float* __restrict__ hw,
                                             const int* __restrict__ row_start,
                                             const int* __restrict__ csr_src,
                                             const float* __restrict__ dst_norm,
                                             const float* __restrict__ bias,
                                             float* __restrict__ out) {
  constexpr int NPW = 64 / D;
  int t = threadIdx.x;
  int lane = t & 63;
  int wave = t >> 6;
  int f   = lane & (D - 1);
  int sub = lane / D;
  int node = (blockIdx.x * 4 + wave) * NPW + sub;
  if (node >= N_NODES) return;
  int start = row_start[node];
  int end   = row_start[node + 1];
  float acc = 0.0f;
  int i = start;
  for (; i + 4 <= end; i += 4) {
    int s0 = csr_src[i + 0];
    int s1 = csr_src[i + 1];
    int s2 = csr_src[i + 2];
    int s3 = csr_src[i + 3];
    float v0 = hw[(size_t)s0 * D + f];
    float v1 = hw[(size_t)s1 * D + f];
    float v2 = hw[(size_t)s2 * D + f];
    float v3 = hw[(size_t)s3 * D + f];
    acc += v0 + v1 + v2 + v3;
  }
  for (; i < end; ++i) acc += hw[(size_t)csr_src[i] * D + f];
  out[(size_t)node * D + f] = fmaxf(acc * dst_norm[node] + bias[f], 0.0f);
}

// ---------------- pooling ----------------
__global__ __launch_bounds__(256) void k_pool(const float* __restrict__ h3,
                                              const int* __restrict__ gid,
                                              float* __restrict__ sums,
                                              float* __restrict__ cnt) {
  const int t = threadIdx.x;
  const int f = t & 15;
  const int grp = t >> 4;
  const int base = blockIdx.x * POOL_NPB;
  float acc = 0.0f, c = 0.0f;
  int cur = gid[base + grp];
#pragma unroll 4
  for (int k = 0; k < POOL_NPB / 16; ++k) {
    int node = base + grp + k * 16;
    int g = gid[node];
    float v = h3[(size_t)node * 16 + f];
    if (g != cur) {
      atomicAdd(&sums[cur * 16 + f], acc);
      if (f == 0) atomicAdd(&cnt[cur], c);
      acc = 0.0f; c = 0.0f; cur = g;
    }
    acc += v; c += 1.0f;
  }
  atomicAdd(&sums[cur * 16 + f], acc);
  if (f == 0) atomicAdd(&cnt[cur], c);
}

__global__ __launch_bounds__(128) void k_classify(const float* __restrict__ sums,
                                                  const float* __restrict__ cnt,
                                                  const float* __restrict__ Wc,
                                                  const float* __restrict__ bc,
                                                  float* __restrict__ out) {
  int g = threadIdx.x;
  float c = cnt[g]; if (c < 1.0f) c = 1.0f;
  float acc = 0.0f;
#pragma unroll
  for (int f = 0; f < 16; ++f) acc += (sums[g * 16 + f] / c) * Wc[f];
  out[g] = acc + bc[0];
}

// ---------------- launch ----------------
extern "C" void kernel_launch(void* const* d_in, const int* in_sizes, int n_in,
                              void* d_out, int out_size, void* d_ws, size_t ws_size,
                              hipStream_t stream) {
  const float* features = (const float*)d_in[0];
  const int*   src      = (const int*)d_in[1];
  const int*   dst      = (const int*)d_in[2];
  const int*   gid      = (const int*)d_in[3];
  const float* W0 = (const float*)d_in[4];
  const float* b0 = (const float*)d_in[5];
  const float* W1 = (const float*)d_in[6];
  const float* b1 = (const float*)d_in[7];
  const float* W2 = (const float*)d_in[8];
  const float* b2 = (const float*)d_in[9];
  const float* Wc = (const float*)d_in[10];
  const float* bc = (const float*)d_in[11];
  float* out = (float*)d_out;

  char* w = (char*)d_ws;
  auto alloc = [&](size_t bytes) {
    void* p = (void*)w;
    w += (bytes + 255) & ~(size_t)255;
    return p;
  };
  int*   outdeg        = (int*)alloc((size_t)N_NODES * 4);
  int*   indeg         = (int*)alloc((size_t)N_NODES * 4);
  float* src_norm      = (float*)alloc((size_t)N_NODES * 4);
  float* dst_norm      = (float*)alloc((size_t)N_NODES * 4);
  int*   row_start     = (int*)alloc((size_t)(N_NODES + 1) * 4);
  int*   partials      = (int*)alloc(512 * 4);
  int*   bucket_cursor = (int*)alloc(NB * 4);
  int*   csr_src       = (int*)alloc((size_t)N_EDGES * 4);
  float* buf0          = (float*)alloc((size_t)N_NODES * 64 * 4);
  float* buf1          = (float*)alloc((size_t)N_NODES * 64 * 4);
  float* sums          = (float*)alloc((size_t)N_GRAPHS * 16 * 4);
  float* cnt           = (float*)alloc((size_t)N_GRAPHS * 4);
  // recs alias: buf0 is not live until k_gemm<256,64>; NB*BUCKET_CAP*8B = 21MB < 33.5MB
  int2* recs = (int2*)buf0;

  hipMemsetAsync(outdeg, 0, (size_t)N_NODES * 2 * 4, stream);
  hipMemsetAsync(sums, 0, (size_t)(N_GRAPHS * 16 + N_GRAPHS) * 4, stream);

  k_init_buckets<<<2, 256, 0, stream>>>(bucket_cursor);
  k_bin<<<N_EDGES / (256 * BIN_EPB), 256, 0, stream>>>(src, dst, outdeg, indeg,
                                                       bucket_cursor, recs);
  k_norms<<<N_NODES / 256, 256, 0, stream>>>(outdeg, indeg, src_norm, dst_norm);
  k_scan_block<<<N_NODES / 256, 256, 0, stream>>>(indeg, row_start, partials);
  k_scan_partials<<<1, 512, 0, stream>>>(partials);
  k_scan_add<<<N_NODES / 256, 256, 0, stream>>>(row_start, partials);
  k_fill2<<<NB, 256, 0, stream>>>(recs, bucket_cursor, row_start, csr_src);

  // layer 0: 256 -> 64
  k_gemm<256, 64><<<N_NODES / 64, 256, 0, stream>>>(features, src_norm, W0, buf0);
  k_agg<64><<<N_NODES / 4, 256, 0, stream>>>(buf0, row_start, csr_src, dst_norm, b0, buf1);
  // layer 1: 64 -> 32
  k_gemm<64, 32><<<N_NODES / 64, 256, 0, stream>>>(buf1, src_norm, W1, buf0);
  k_agg<32><<<N_NODES / 8, 256, 0, stream>>>(buf0, row_start, csr_src, dst_norm, b1, buf1);
  // layer 2: 32 -> 16
  k_gemm<32, 16><<<N_NODES / 64, 256, 0, stream>>>(buf1, src_norm, W2, buf0);
  k_agg<16><<<N_NODES / 16, 256, 0, stream>>>(buf0, row_start, csr_src, dst_norm, b2, buf1);

  k_pool<<<N_NODES / POOL_NPB, 256, 0, stream>>>(buf1, gid, sums, cnt);
  k_classify<<<1, 128, 0, stream>>>(sums, cnt, Wc, bc, out);
}

// Round 5
// 518.391 us; speedup vs baseline: 2.5285x; 1.0032x over previous
//
#include <hip/hip_runtime.h>

#define N_NODES 131072
#define N_EDGES 2097152
#define N_GRAPHS 128
#define POOL_NPB 256       // nodes per block in k_pool
#define NB 256             // CSR buckets
#define BUCKET_SHIFT 9     // 512 nodes per bucket (131072/256)
#define BUCKET_CAP 9728    // max edges per bucket (mean 8192, +17 sigma)
#define BIN_EPT 32         // edges per thread per pass in k_bin (8192/block)

__global__ __launch_bounds__(256) void k_norms(const int* __restrict__ outdeg,
                                               const int* __restrict__ indeg,
                                               float* __restrict__ src_norm,
                                               float* __restrict__ dst_norm) {
  int n = blockIdx.x * 256 + threadIdx.x;
  int od = outdeg[n]; if (od < 1) od = 1;
  int id = indeg[n];  if (id < 1) id = 1;
  src_norm[n] = 1.0f / sqrtf((float)od);
  dst_norm[n] = 1.0f / sqrtf((float)id);
}

// ---------------- scan (exclusive prefix sum of indeg -> row_start) ----------------
__global__ __launch_bounds__(256) void k_scan_block(const int* __restrict__ indeg,
                                                    int* __restrict__ row_start,
                                                    int* __restrict__ partials) {
  __shared__ int tmp[256];
  int t = threadIdx.x;
  int n = blockIdx.x * 256 + t;
  int v = indeg[n];
  tmp[t] = v;
  __syncthreads();
  for (int off = 1; off < 256; off <<= 1) {
    int x = (t >= off) ? tmp[t - off] : 0;
    __syncthreads();
    tmp[t] += x;
    __syncthreads();
  }
  row_start[n] = tmp[t] - v;            // exclusive
  if (t == 255) partials[blockIdx.x] = tmp[t];
}

__global__ __launch_bounds__(512) void k_scan_partials(int* __restrict__ partials) {
  __shared__ int tmp[512];
  int t = threadIdx.x;
  int v = partials[t];
  tmp[t] = v;
  __syncthreads();
  for (int off = 1; off < 512; off <<= 1) {
    int x = (t >= off) ? tmp[t - off] : 0;
    __syncthreads();
    tmp[t] += x;
    __syncthreads();
  }
  partials[t] = tmp[t] - v;             // exclusive block offsets
}

__global__ __launch_bounds__(256) void k_scan_add(int* __restrict__ row_start,
                                                  const int* __restrict__ partials) {
  int n = blockIdx.x * 256 + threadIdx.x;
  row_start[n] += partials[blockIdx.x];
  if (n == 0) row_start[N_NODES] = N_EDGES;
}

// ---------------- bucket init ----------------
__global__ __launch_bounds__(256) void k_init_buckets(int* __restrict__ bucket_cursor) {
  int i = threadIdx.x;
  bucket_cursor[i] = i * BUCKET_CAP;
}

// ---------------- phase A: bin edges by dst bucket, count degrees (two-pass) ----
// Grid=256 blocks so per-(block,bucket) runs are ~512B and the per-XCD L2 line
// assembly window (~32 resident blocks x 256 lines) is ~1MB << 4MB L2.
__global__ __launch_bounds__(256) void k_bin(const int* __restrict__ src,
                                             const int* __restrict__ dst,
                                             int* __restrict__ outdeg,
                                             int* __restrict__ indeg,
                                             int* __restrict__ bucket_cursor,
                                             int2* __restrict__ recs) {
  __shared__ int hist[NB];
  const int t = threadIdx.x;
  const int e0 = blockIdx.x * (256 * BIN_EPT);
  hist[t] = 0;                  // NB == blockDim == 256
  __syncthreads();
#pragma unroll 4
  for (int k = 0; k < BIN_EPT; ++k) {
    int e = e0 + k * 256 + t;
    int s = src[e];
    int d = dst[e];
    atomicAdd(&hist[d >> BUCKET_SHIFT], 1);
    atomicAdd(&outdeg[s], 1);
    atomicAdd(&indeg[d], 1);
  }
  __syncthreads();
  {
    int c = hist[t];
    int g = c ? atomicAdd(&bucket_cursor[t], c) : 0;
    hist[t] = g;                // repurpose as LDS write cursor (global offset)
  }
  __syncthreads();
#pragma unroll 4
  for (int k = 0; k < BIN_EPT; ++k) {
    int e = e0 + k * 256 + t;   // re-read (L2/L3 hot)
    int s = src[e];
    int d = dst[e];
    int p = atomicAdd(&hist[d >> BUCKET_SHIFT], 1);
    recs[p] = make_int2(s, d);
  }
}

// ---------------- phase B: per-bucket CSR fill with LDS cursors ----------------
__global__ __launch_bounds__(256) void k_fill2(const int2* __restrict__ recs,
                                               const int* __restrict__ bucket_cursor,
                                               const int* __restrict__ row_start,
                                               int* __restrict__ csr_src) {
  __shared__ int lcur[512];
  const int b = blockIdx.x;
  const int t = threadIdx.x;
  lcur[t]       = row_start[b * 512 + t];
  lcur[t + 256] = row_start[b * 512 + t + 256];
  __syncthreads();
  const int beg = b * BUCKET_CAP;
  const int end = bucket_cursor[b];     // beg + count
  for (int i = beg + t; i < end; i += 256) {
    int2 r = recs[i];
    int p = atomicAdd(&lcur[r.y & 511], 1);
    csr_src[p] = r.x;
  }
}

// ---------------- GEMM: out[N,DOUT] = (h * src_norm) @ W ----------------
template <int DIN, int DOUT>
__global__ __launch_bounds__(256) void k_gemm(const float* __restrict__ h,
                                              const float* __restrict__ src_norm,
                                              const float* __restrict__ W,
                                              float* __restrict__ out) {
  constexpr int KC   = (DIN < 64) ? DIN : 64;
  constexpr int ROWS = 64;
  constexpr int TN   = DOUT / 16;
  __shared__ float hT[KC][ROWS + 4];
  __shared__ float Ws[KC][DOUT];

  const int t = threadIdx.x;
  const int rowBase = blockIdx.x * ROWS;
  const int tr = t & 15;
  const int tc = t >> 4;

  float acc[4][TN];
#pragma unroll
  for (int i = 0; i < 4; ++i)
#pragma unroll
    for (int j = 0; j < TN; ++j) acc[i][j] = 0.0f;

  for (int kc = 0; kc < DIN; kc += KC) {
    constexpr int ELEMS = KC * ROWS;
#pragma unroll
    for (int base = 0; base < ELEMS; base += 256 * 4) {
      int idx = base + t * 4;
      if (idx < ELEMS) {
        int r  = idx / KC;
        int kk = idx % KC;
        float4 v = *reinterpret_cast<const float4*>(&h[(size_t)(rowBase + r) * DIN + kc + kk]);
        float nrm = src_norm[rowBase + r];
        hT[kk + 0][r] = v.x * nrm;
        hT[kk + 1][r] = v.y * nrm;
        hT[kk + 2][r] = v.z * nrm;
        hT[kk + 3][r] = v.w * nrm;
      }
    }
    constexpr int WEL = KC * DOUT;
#pragma unroll
    for (int base = 0; base < WEL; base += 256 * 4) {
      int idx = base + t * 4;
      if (idx < WEL) {
        int kk = idx / DOUT;
        int c  = idx % DOUT;
        *reinterpret_cast<float4*>(&Ws[kk][c]) =
            *reinterpret_cast<const float4*>(&W[(size_t)(kc + kk) * DOUT + c]);
      }
    }
    __syncthreads();
#pragma unroll
    for (int kk = 0; kk < KC; ++kk) {
      float a[4], bb[TN];
#pragma unroll
      for (int i = 0; i < 4; ++i) a[i] = hT[kk][tr * 4 + i];
#pragma unroll
      for (int j = 0; j < TN; ++j) bb[j] = Ws[kk][tc * TN + j];
#pragma unroll
      for (int i = 0; i < 4; ++i)
#pragma unroll
        for (int j = 0; j < TN; ++j) acc[i][j] += a[i] * bb[j];
    }
    __syncthreads();
  }
#pragma unroll
  for (int i = 0; i < 4; ++i) {
    int row = rowBase + tr * 4 + i;
#pragma unroll
    for (int j = 0; j < TN; ++j)
      out[(size_t)row * DOUT + tc * TN + j] = acc[i][j];
  }
}

// ---------------- aggregation: out = relu(segment_sum(hw[csr]) * dst_norm + b) ----------------
template <int D>
__global__ __launch_bounds__(256) void k_agg(const float* __restrict__ hw,
                                             const int* __restrict__ row_start,
                                             const int* __restrict__ csr_src,
                                             const float* __restrict__ dst_norm,
                                             const float* __restrict__ bias,
                                             float* __restrict__ out) {
  constexpr int NPW = 64 / D;
  int t = threadIdx.x;
  int lane = t & 63;
  int wave = t >> 6;
  int f   = lane & (D - 1);
  int sub = lane / D;
  int node = (blockIdx.x * 4 + wave) * NPW + sub;
  if (node >= N_NODES) return;
  int start = row_start[node];
  int end   = row_start[node + 1];
  float acc = 0.0f;
  int i = start;
  for (; i + 4 <= end; i += 4) {
    int s0 = csr_src[i + 0];
    int s1 = csr_src[i + 1];
    int s2 = csr_src[i + 2];
    int s3 = csr_src[i + 3];
    float v0 = hw[(size_t)s0 * D + f];
    float v1 = hw[(size_t)s1 * D + f];
    float v2 = hw[(size_t)s2 * D + f];
    float v3 = hw[(size_t)s3 * D + f];
    acc += v0 + v1 + v2 + v3;
  }
  for (; i < end; ++i) acc += hw[(size_t)csr_src[i] * D + f];
  out[(size_t)node * D + f] = fmaxf(acc * dst_norm[node] + bias[f], 0.0f);
}

// ---------------- pooling ----------------
__global__ __launch_bounds__(256) void k_pool(const float* __restrict__ h3,
                                              const int* __restrict__ gid,
                                              float* __restrict__ sums,
                                              float* __restrict__ cnt) {
  const int t = threadIdx.x;
  const int f = t & 15;
  const int grp = t >> 4;
  const int base = blockIdx.x * POOL_NPB;
  float acc = 0.0f, c = 0.0f;
  int cur = gid[base + grp];
#pragma unroll 4
  for (int k = 0; k < POOL_NPB / 16; ++k) {
    int node = base + grp + k * 16;
    int g = gid[node];
    float v = h3[(size_t)node * 16 + f];
    if (g != cur) {
      atomicAdd(&sums[cur * 16 + f], acc);
      if (f == 0) atomicAdd(&cnt[cur], c);
      acc = 0.0f; c = 0.0f; cur = g;
    }
    acc += v; c += 1.0f;
  }
  atomicAdd(&sums[cur * 16 + f], acc);
  if (f == 0) atomicAdd(&cnt[cur], c);
}

__global__ __launch_bounds__(128) void k_classify(const float* __restrict__ sums,
                                                  const float* __restrict__ cnt,
                                                  const float* __restrict__ Wc,
                                                  const float* __restrict__ bc,
                                                  float* __restrict__ out) {
  int g = threadIdx.x;
  float c = cnt[g]; if (c < 1.0f) c = 1.0f;
  float acc = 0.0f;
#pragma unroll
  for (int f = 0; f < 16; ++f) acc += (sums[g * 16 + f] / c) * Wc[f];
  out[g] = acc + bc[0];
}

// ---------------- launch ----------------
extern "C" void kernel_launch(void* const* d_in, const int* in_sizes, int n_in,
                              void* d_out, int out_size, void* d_ws, size_t ws_size,
                              hipStream_t stream) {
  const float* features = (const float*)d_in[0];
  const int*   src      = (const int*)d_in[1];
  const int*   dst      = (const int*)d_in[2];
  const int*   gid      = (const int*)d_in[3];
  const float* W0 = (const float*)d_in[4];
  const float* b0 = (const float*)d_in[5];
  const float* W1 = (const float*)d_in[6];
  const float* b1 = (const float*)d_in[7];
  const float* W2 = (const float*)d_in[8];
  const float* b2 = (const float*)d_in[9];
  const float* Wc = (const float*)d_in[10];
  const float* bc = (const float*)d_in[11];
  float* out = (float*)d_out;

  char* w = (char*)d_ws;
  auto alloc = [&](size_t bytes) {
    void* p = (void*)w;
    w += (bytes + 255) & ~(size_t)255;
    return p;
  };
  int*   outdeg        = (int*)alloc((size_t)N_NODES * 4);
  int*   indeg         = (int*)alloc((size_t)N_NODES * 4);
  float* src_norm      = (float*)alloc((size_t)N_NODES * 4);
  float* dst_norm      = (float*)alloc((size_t)N_NODES * 4);
  int*   row_start     = (int*)alloc((size_t)(N_NODES + 1) * 4);
  int*   partials      = (int*)alloc(512 * 4);
  int*   bucket_cursor = (int*)alloc(NB * 4);
  int*   csr_src       = (int*)alloc((size_t)N_EDGES * 4);
  float* buf0          = (float*)alloc((size_t)N_NODES * 64 * 4);
  float* buf1          = (float*)alloc((size_t)N_NODES * 64 * 4);
  float* sums          = (float*)alloc((size_t)N_GRAPHS * 16 * 4);
  float* cnt           = (float*)alloc((size_t)N_GRAPHS * 4);
  // recs alias: buf0 not live until k_gemm<256,64>; NB*BUCKET_CAP*8B = 19.9MB < 33.5MB
  int2* recs = (int2*)buf0;

  hipMemsetAsync(outdeg, 0, (size_t)N_NODES * 2 * 4, stream);
  hipMemsetAsync(sums, 0, (size_t)(N_GRAPHS * 16 + N_GRAPHS) * 4, stream);

  k_init_buckets<<<1, NB, 0, stream>>>(bucket_cursor);
  k_bin<<<N_EDGES / (256 * BIN_EPT), 256, 0, stream>>>(src, dst, outdeg, indeg,
                                                       bucket_cursor, recs);
  k_norms<<<N_NODES / 256, 256, 0, stream>>>(outdeg, indeg, src_norm, dst_norm);
  k_scan_block<<<N_NODES / 256, 256, 0, stream>>>(indeg, row_start, partials);
  k_scan_partials<<<1, 512, 0, stream>>>(partials);
  k_scan_add<<<N_NODES / 256, 256, 0, stream>>>(row_start, partials);
  k_fill2<<<NB, 256, 0, stream>>>(recs, bucket_cursor, row_start, csr_src);

  // layer 0: 256 -> 64
  k_gemm<256, 64><<<N_NODES / 64, 256, 0, stream>>>(features, src_norm, W0, buf0);
  k_agg<64><<<N_NODES / 4, 256, 0, stream>>>(buf0, row_start, csr_src, dst_norm, b0, buf1);
  // layer 1: 64 -> 32
  k_gemm<64, 32><<<N_NODES / 64, 256, 0, stream>>>(buf1, src_norm, W1, buf0);
  k_agg<32><<<N_NODES / 8, 256, 0, stream>>>(buf0, row_start, csr_src, dst_norm, b1, buf1);
  // layer 2: 32 -> 16
  k_gemm<32, 16><<<N_NODES / 64, 256, 0, stream>>>(buf1, src_norm, W2, buf0);
  k_agg<16><<<N_NODES / 16, 256, 0, stream>>>(buf0, row_start, csr_src, dst_norm, b2, buf1);

  k_pool<<<N_NODES / POOL_NPB, 256, 0, stream>>>(buf1, gid, sums, cnt);
  k_classify<<<1, 128, 0, stream>>>(sums, cnt, Wc, bc, out);
}

// Round 6
// 384.803 us; speedup vs baseline: 3.4063x; 1.3472x over previous
//
#include <hip/hip_runtime.h>

#define N_NODES 131072
#define N_EDGES 2097152
#define N_GRAPHS 128
#define POOL_NPB 256       // nodes per block in k_pool
#define NB 256             // buckets (both src- and dst-binning)
#define BUCKET_SHIFT 9     // 512 nodes per bucket
#define BUCKET_CAP 9728    // max edges per bucket (mean 8192, +17 sigma)
#define BIN_EPT 32         // edges per thread per pass in k_bin (8192/block)

// ---------------- bucket cursor init ----------------
__global__ __launch_bounds__(256) void k_init_buckets(int* __restrict__ cursor_d,
                                                      int* __restrict__ cursor_s) {
  int i = threadIdx.x;
  cursor_d[i] = i * BUCKET_CAP;
  cursor_s[i] = i * BUCKET_CAP;
}

// ---------------- phase A: bin edges (two-pass, ZERO per-edge global atomics) ----
// dst-records: (src<<9)|(dst&511) packed u32, binned by dst>>9.
// src-records: (src&511) as u16, binned by src>>9 (for outdeg counting).
__global__ __launch_bounds__(256) void k_bin(const int* __restrict__ src,
                                             const int* __restrict__ dst,
                                             int* __restrict__ cursor_d,
                                             int* __restrict__ cursor_s,
                                             unsigned int* __restrict__ recs_d,
                                             unsigned short* __restrict__ recs_s) {
  __shared__ int hd[NB];
  __shared__ int hs[NB];
  const int t = threadIdx.x;
  const int e0 = blockIdx.x * (256 * BIN_EPT);
  hd[t] = 0; hs[t] = 0;
  __syncthreads();
#pragma unroll 4
  for (int k = 0; k < BIN_EPT; ++k) {
    int e = e0 + k * 256 + t;
    atomicAdd(&hd[dst[e] >> BUCKET_SHIFT], 1);
    atomicAdd(&hs[src[e] >> BUCKET_SHIFT], 1);
  }
  __syncthreads();
  { int c = hd[t]; hd[t] = c ? atomicAdd(&cursor_d[t], c) : 0; }
  { int c = hs[t]; hs[t] = c ? atomicAdd(&cursor_s[t], c) : 0; }
  __syncthreads();
#pragma unroll 4
  for (int k = 0; k < BIN_EPT; ++k) {
    int e = e0 + k * 256 + t;      // re-read (L2/L3 hot)
    int s = src[e];
    int d = dst[e];
    int pd = atomicAdd(&hd[d >> BUCKET_SHIFT], 1);
    recs_d[pd] = ((unsigned int)s << BUCKET_SHIFT) | (unsigned int)(d & 511);
    int ps = atomicAdd(&hs[s >> BUCKET_SHIFT], 1);
    recs_s[ps] = (unsigned short)(s & 511);
  }
}

// ---------------- outdeg via LDS histogram -> src_norm ----------------
__global__ __launch_bounds__(512) void k_outdeg(const unsigned short* __restrict__ recs_s,
                                                const int* __restrict__ cursor_s,
                                                float* __restrict__ src_norm) {
  __shared__ int hist[512];
  const int b = blockIdx.x;
  const int t = threadIdx.x;
  hist[t] = 0;
  __syncthreads();
  const int beg = b * BUCKET_CAP;
  const int end = cursor_s[b];
  for (int i = beg + t; i < end; i += 512) atomicAdd(&hist[recs_s[i]], 1);
  __syncthreads();
  int od = hist[t]; if (od < 1) od = 1;
  src_norm[b * 512 + t] = 1.0f / sqrtf((float)od);
}

// ---------------- bucket base: exclusive scan of dst-bucket counts ----------------
__global__ __launch_bounds__(256) void k_bucket_scan(const int* __restrict__ cursor_d,
                                                     int* __restrict__ bucket_base,
                                                     int* __restrict__ row_start) {
  __shared__ int tmp[256];
  int t = threadIdx.x;
  int c = cursor_d[t] - t * BUCKET_CAP;   // count in bucket t
  tmp[t] = c;
  __syncthreads();
  for (int off = 1; off < 256; off <<= 1) {
    int x = (t >= off) ? tmp[t - off] : 0;
    __syncthreads();
    tmp[t] += x;
    __syncthreads();
  }
  bucket_base[t] = tmp[t] - c;            // exclusive
  if (t == 0) row_start[N_NODES] = N_EDGES;
}

// ---------------- phase B: indeg+row_start+dst_norm+CSR fill, all in LDS --------
__global__ __launch_bounds__(512) void k_fill2(const unsigned int* __restrict__ recs_d,
                                               const int* __restrict__ cursor_d,
                                               const int* __restrict__ bucket_base,
                                               int* __restrict__ row_start,
                                               float* __restrict__ dst_norm,
                                               int* __restrict__ csr_src) {
  __shared__ int hist[512];
  __shared__ int lcur[512];
  const int b = blockIdx.x;
  const int t = threadIdx.x;
  hist[t] = 0;
  __syncthreads();
  const int beg = b * BUCKET_CAP;
  const int end = cursor_d[b];
  for (int i = beg + t; i < end; i += 512) atomicAdd(&hist[recs_d[i] & 511], 1);
  __syncthreads();
  int deg = hist[t];
  // inclusive scan over 512 in lcur
  lcur[t] = deg;
  __syncthreads();
  for (int off = 1; off < 512; off <<= 1) {
    int x = (t >= off) ? lcur[t - off] : 0;
    __syncthreads();
    lcur[t] += x;
    __syncthreads();
  }
  int rs = bucket_base[b] + lcur[t] - deg;   // global exclusive offset for node b*512+t
  row_start[b * 512 + t] = rs;
  int dd = deg < 1 ? 1 : deg;
  dst_norm[b * 512 + t] = 1.0f / sqrtf((float)dd);
  lcur[t] = rs;                               // repurpose as write cursor
  __syncthreads();
  for (int i = beg + t; i < end; i += 512) {
    unsigned int r = recs_d[i];
    int p = atomicAdd(&lcur[r & 511], 1);
    csr_src[p] = (int)(r >> BUCKET_SHIFT);
  }
}

// ---------------- GEMM: out[N,DOUT] = (h * src_norm) @ W ----------------
template <int DIN, int DOUT>
__global__ __launch_bounds__(256) void k_gemm(const float* __restrict__ h,
                                              const float* __restrict__ src_norm,
                                              const float* __restrict__ W,
                                              float* __restrict__ out) {
  constexpr int KC   = (DIN < 64) ? DIN : 64;
  constexpr int ROWS = 64;
  constexpr int TN   = DOUT / 16;
  __shared__ float hT[KC][ROWS + 4];
  __shared__ float Ws[KC][DOUT];

  const int t = threadIdx.x;
  const int rowBase = blockIdx.x * ROWS;
  const int tr = t & 15;
  const int tc = t >> 4;

  float acc[4][TN];
#pragma unroll
  for (int i = 0; i < 4; ++i)
#pragma unroll
    for (int j = 0; j < TN; ++j) acc[i][j] = 0.0f;

  for (int kc = 0; kc < DIN; kc += KC) {
    constexpr int ELEMS = KC * ROWS;
#pragma unroll
    for (int base = 0; base < ELEMS; base += 256 * 4) {
      int idx = base + t * 4;
      if (idx < ELEMS) {
        int r  = idx / KC;
        int kk = idx % KC;
        float4 v = *reinterpret_cast<const float4*>(&h[(size_t)(rowBase + r) * DIN + kc + kk]);
        float nrm = src_norm[rowBase + r];
        hT[kk + 0][r] = v.x * nrm;
        hT[kk + 1][r] = v.y * nrm;
        hT[kk + 2][r] = v.z * nrm;
        hT[kk + 3][r] = v.w * nrm;
      }
    }
    constexpr int WEL = KC * DOUT;
#pragma unroll
    for (int base = 0; base < WEL; base += 256 * 4) {
      int idx = base + t * 4;
      if (idx < WEL) {
        int kk = idx / DOUT;
        int c  = idx % DOUT;
        *reinterpret_cast<float4*>(&Ws[kk][c]) =
            *reinterpret_cast<const float4*>(&W[(size_t)(kc + kk) * DOUT + c]);
      }
    }
    __syncthreads();
#pragma unroll
    for (int kk = 0; kk < KC; ++kk) {
      float a[4], bb[TN];
#pragma unroll
      for (int i = 0; i < 4; ++i) a[i] = hT[kk][tr * 4 + i];
#pragma unroll
      for (int j = 0; j < TN; ++j) bb[j] = Ws[kk][tc * TN + j];
#pragma unroll
      for (int i = 0; i < 4; ++i)
#pragma unroll
        for (int j = 0; j < TN; ++j) acc[i][j] += a[i] * bb[j];
    }
    __syncthreads();
  }
#pragma unroll
  for (int i = 0; i < 4; ++i) {
    int row = rowBase + tr * 4 + i;
#pragma unroll
    for (int j = 0; j < TN; ++j)
      out[(size_t)row * DOUT + tc * TN + j] = acc[i][j];
  }
}

// ---------------- aggregation: out = relu(segment_sum(hw[csr]) * dst_norm + b) ----------------
template <int D>
__global__ __launch_bounds__(256) void k_agg(const float* __restrict__ hw,
                                             const int* __restrict__ row_start,
                                             const int* __restrict__ csr_src,
                                             const float* __restrict__ dst_norm,
                                             const float* __restrict__ bias,
                                             float* __restrict__ out) {
  constexpr int NPW = 64 / D;
  int t = threadIdx.x;
  int lane = t & 63;
  int wave = t >> 6;
  int f   = lane & (D - 1);
  int sub = lane / D;
  int node = (blockIdx.x * 4 + wave) * NPW + sub;
  if (node >= N_NODES) return;
  int start = row_start[node];
  int end   = row_start[node + 1];
  float acc = 0.0f;
  int i = start;
  for (; i + 4 <= end; i += 4) {
    int s0 = csr_src[i + 0];
    int s1 = csr_src[i + 1];
    int s2 = csr_src[i + 2];
    int s3 = csr_src[i + 3];
    float v0 = hw[(size_t)s0 * D + f];
    float v1 = hw[(size_t)s1 * D + f];
    float v2 = hw[(size_t)s2 * D + f];
    float v3 = hw[(size_t)s3 * D + f];
    acc += v0 + v1 + v2 + v3;
  }
  for (; i < end; ++i) acc += hw[(size_t)csr_src[i] * D + f];
  out[(size_t)node * D + f] = fmaxf(acc * dst_norm[node] + bias[f], 0.0f);
}

// ---------------- pooling ----------------
__global__ __launch_bounds__(256) void k_pool(const float* __restrict__ h3,
                                              const int* __restrict__ gid,
                                              float* __restrict__ sums,
                                              float* __restrict__ cnt) {
  const int t = threadIdx.x;
  const int f = t & 15;
  const int grp = t >> 4;
  const int base = blockIdx.x * POOL_NPB;
  float acc = 0.0f, c = 0.0f;
  int cur = gid[base + grp];
#pragma unroll 4
  for (int k = 0; k < POOL_NPB / 16; ++k) {
    int node = base + grp + k * 16;
    int g = gid[node];
    float v = h3[(size_t)node * 16 + f];
    if (g != cur) {
      atomicAdd(&sums[cur * 16 + f], acc);
      if (f == 0) atomicAdd(&cnt[cur], c);
      acc = 0.0f; c = 0.0f; cur = g;
    }
    acc += v; c += 1.0f;
  }
  atomicAdd(&sums[cur * 16 + f], acc);
  if (f == 0) atomicAdd(&cnt[cur], c);
}

__global__ __launch_bounds__(128) void k_classify(const float* __restrict__ sums,
                                                  const float* __restrict__ cnt,
                                                  const float* __restrict__ Wc,
                                                  const float* __restrict__ bc,
                                                  float* __restrict__ out) {
  int g = threadIdx.x;
  float c = cnt[g]; if (c < 1.0f) c = 1.0f;
  float acc = 0.0f;
#pragma unroll
  for (int f = 0; f < 16; ++f) acc += (sums[g * 16 + f] / c) * Wc[f];
  out[g] = acc + bc[0];
}

// ---------------- launch ----------------
extern "C" void kernel_launch(void* const* d_in, const int* in_sizes, int n_in,
                              void* d_out, int out_size, void* d_ws, size_t ws_size,
                              hipStream_t stream) {
  const float* features = (const float*)d_in[0];
  const int*   src      = (const int*)d_in[1];
  const int*   dst      = (const int*)d_in[2];
  const int*   gid      = (const int*)d_in[3];
  const float* W0 = (const float*)d_in[4];
  const float* b0 = (const float*)d_in[5];
  const float* W1 = (const float*)d_in[6];
  const float* b1 = (const float*)d_in[7];
  const float* W2 = (const float*)d_in[8];
  const float* b2 = (const float*)d_in[9];
  const float* Wc = (const float*)d_in[10];
  const float* bc = (const float*)d_in[11];
  float* out = (float*)d_out;

  char* w = (char*)d_ws;
  auto alloc = [&](size_t bytes) {
    void* p = (void*)w;
    w += (bytes + 255) & ~(size_t)255;
    return p;
  };
  float* src_norm    = (float*)alloc((size_t)N_NODES * 4);
  float* dst_norm    = (float*)alloc((size_t)N_NODES * 4);
  int*   row_start   = (int*)alloc((size_t)(N_NODES + 1) * 4);
  int*   cursor_d    = (int*)alloc(NB * 4);
  int*   cursor_s    = (int*)alloc(NB * 4);
  int*   bucket_base = (int*)alloc(NB * 4);
  int*   csr_src     = (int*)alloc((size_t)N_EDGES * 4);
  float* buf0        = (float*)alloc((size_t)N_NODES * 64 * 4);
  float* buf1        = (float*)alloc((size_t)N_NODES * 64 * 4);
  float* sums        = (float*)alloc((size_t)N_GRAPHS * 16 * 4);
  float* cnt         = (float*)alloc((size_t)N_GRAPHS * 4);
  // aliases: buf0/buf1 are not live until the GEMM/agg phase.
  unsigned int*   recs_d = (unsigned int*)buf0;    // NB*CAP*4B = 10.0 MB < 33.5 MB
  unsigned short* recs_s = (unsigned short*)buf1;  // NB*CAP*2B =  5.0 MB < 33.5 MB

  hipMemsetAsync(sums, 0, (size_t)(N_GRAPHS * 16 + N_GRAPHS) * 4, stream);

  k_init_buckets<<<1, 256, 0, stream>>>(cursor_d, cursor_s);
  k_bin<<<N_EDGES / (256 * BIN_EPT), 256, 0, stream>>>(src, dst, cursor_d, cursor_s,
                                                       recs_d, recs_s);
  k_outdeg<<<NB, 512, 0, stream>>>(recs_s, cursor_s, src_norm);
  k_bucket_scan<<<1, 256, 0, stream>>>(cursor_d, bucket_base, row_start);
  k_fill2<<<NB, 512, 0, stream>>>(recs_d, cursor_d, bucket_base, row_start,
                                  dst_norm, csr_src);

  // layer 0: 256 -> 64
  k_gemm<256, 64><<<N_NODES / 64, 256, 0, stream>>>(features, src_norm, W0, buf0);
  k_agg<64><<<N_NODES / 4, 256, 0, stream>>>(buf0, row_start, csr_src, dst_norm, b0, buf1);
  // layer 1: 64 -> 32
  k_gemm<64, 32><<<N_NODES / 64, 256, 0, stream>>>(buf1, src_norm, W1, buf0);
  k_agg<32><<<N_NODES / 8, 256, 0, stream>>>(buf0, row_start, csr_src, dst_norm, b1, buf1);
  // layer 2: 32 -> 16
  k_gemm<32, 16><<<N_NODES / 64, 256, 0, stream>>>(buf1, src_norm, W2, buf0);
  k_agg<16><<<N_NODES / 16, 256, 0, stream>>>(buf0, row_start, csr_src, dst_norm, b2, buf1);

  k_pool<<<N_NODES / POOL_NPB, 256, 0, stream>>>(buf1, gid, sums, cnt);
  k_classify<<<1, 128, 0, stream>>>(sums, cnt, Wc, bc, out);
}

// Round 7
// 341.777 us; speedup vs baseline: 3.8352x; 1.1259x over previous
//
#include <hip/hip_runtime.h>

#define N_NODES 131072
#define N_EDGES 2097152
#define N_GRAPHS 128
#define POOL_NPB 256       // nodes per block in k_pool
#define NB 256             // buckets (both src- and dst-binning)
#define BUCKET_SHIFT 9     // 512 nodes per bucket
#define BUCKET_CAP 9728    // max edges per bucket (mean 8192, +17 sigma)
#define BIN_EPT 32         // edges per thread per pass in k_bin (8192/block)

// ---------------- bucket cursor init ----------------
__global__ __launch_bounds__(256) void k_init_buckets(int* __restrict__ cursor_d,
                                                      int* __restrict__ cursor_s) {
  int i = threadIdx.x;
  cursor_d[i] = i * BUCKET_CAP;
  cursor_s[i] = i * BUCKET_CAP;
}

// ---------------- phase A: bin edges (two-pass, zero per-edge global atomics) ----
__global__ __launch_bounds__(256) void k_bin(const int* __restrict__ src,
                                             const int* __restrict__ dst,
                                             int* __restrict__ cursor_d,
                                             int* __restrict__ cursor_s,
                                             unsigned int* __restrict__ recs_d,
                                             unsigned short* __restrict__ recs_s) {
  __shared__ int hd[NB];
  __shared__ int hs[NB];
  const int t = threadIdx.x;
  const int e0 = blockIdx.x * (256 * BIN_EPT);
  hd[t] = 0; hs[t] = 0;
  __syncthreads();
#pragma unroll 4
  for (int k = 0; k < BIN_EPT; ++k) {
    int e = e0 + k * 256 + t;
    atomicAdd(&hd[dst[e] >> BUCKET_SHIFT], 1);
    atomicAdd(&hs[src[e] >> BUCKET_SHIFT], 1);
  }
  __syncthreads();
  { int c = hd[t]; hd[t] = c ? atomicAdd(&cursor_d[t], c) : 0; }
  { int c = hs[t]; hs[t] = c ? atomicAdd(&cursor_s[t], c) : 0; }
  __syncthreads();
#pragma unroll 4
  for (int k = 0; k < BIN_EPT; ++k) {
    int e = e0 + k * 256 + t;      // re-read (L2/L3 hot)
    int s = src[e];
    int d = dst[e];
    int pd = atomicAdd(&hd[d >> BUCKET_SHIFT], 1);
    recs_d[pd] = ((unsigned int)s << BUCKET_SHIFT) | (unsigned int)(d & 511);
    int ps = atomicAdd(&hs[s >> BUCKET_SHIFT], 1);
    recs_s[ps] = (unsigned short)(s & 511);
  }
}

// ---------------- outdeg via LDS histogram -> src_norm ----------------
__global__ __launch_bounds__(512) void k_outdeg(const unsigned short* __restrict__ recs_s,
                                                const int* __restrict__ cursor_s,
                                                float* __restrict__ src_norm) {
  __shared__ int hist[512];
  const int b = blockIdx.x;
  const int t = threadIdx.x;
  hist[t] = 0;
  __syncthreads();
  const int beg = b * BUCKET_CAP;
  const int end = cursor_s[b];
  for (int i = beg + t; i < end; i += 512) atomicAdd(&hist[recs_s[i]], 1);
  __syncthreads();
  int od = hist[t]; if (od < 1) od = 1;
  src_norm[b * 512 + t] = 1.0f / sqrtf((float)od);
}

// ---------------- bucket base: exclusive scan of dst-bucket counts ----------------
__global__ __launch_bounds__(256) void k_bucket_scan(const int* __restrict__ cursor_d,
                                                     int* __restrict__ bucket_base,
                                                     int* __restrict__ row_start) {
  __shared__ int tmp[256];
  int t = threadIdx.x;
  int c = cursor_d[t] - t * BUCKET_CAP;
  tmp[t] = c;
  __syncthreads();
  for (int off = 1; off < 256; off <<= 1) {
    int x = (t >= off) ? tmp[t - off] : 0;
    __syncthreads();
    tmp[t] += x;
    __syncthreads();
  }
  bucket_base[t] = tmp[t] - c;
  if (t == 0) row_start[N_NODES] = N_EDGES;
}

// ---------------- phase B: indeg+row_start+dst_norm+CSR fill, all in LDS --------
__global__ __launch_bounds__(512) void k_fill2(const unsigned int* __restrict__ recs_d,
                                               const int* __restrict__ cursor_d,
                                               const int* __restrict__ bucket_base,
                                               int* __restrict__ row_start,
                                               float* __restrict__ dst_norm,
                                               int* __restrict__ csr_src) {
  __shared__ int hist[512];
  __shared__ int lcur[512];
  const int b = blockIdx.x;
  const int t = threadIdx.x;
  hist[t] = 0;
  __syncthreads();
  const int beg = b * BUCKET_CAP;
  const int end = cursor_d[b];
  for (int i = beg + t; i < end; i += 512) atomicAdd(&hist[recs_d[i] & 511], 1);
  __syncthreads();
  int deg = hist[t];
  lcur[t] = deg;
  __syncthreads();
  for (int off = 1; off < 512; off <<= 1) {
    int x = (t >= off) ? lcur[t - off] : 0;
    __syncthreads();
    lcur[t] += x;
    __syncthreads();
  }
  int rs = bucket_base[b] + lcur[t] - deg;
  row_start[b * 512 + t] = rs;
  int dd = deg < 1 ? 1 : deg;
  dst_norm[b * 512 + t] = 1.0f / sqrtf((float)dd);
  lcur[t] = rs;
  __syncthreads();
  for (int i = beg + t; i < end; i += 512) {
    unsigned int r = recs_d[i];
    int p = atomicAdd(&lcur[r & 511], 1);
    csr_src[p] = (int)(r >> BUCKET_SHIFT);
  }
}

// ---------------- GEMM v2: out[N,DOUT] = (h * src_norm) @ W ----------------
// 128-row tile, KC=32. hT[32][128] transposed, XOR-swizzled (r ^= ((kk>>3)&3)<<3)
// so staging writes spread over banks {0,8,16,24} (conflict-free) while A-reads
// stay 16B-contiguous b128 at 2-way bank aliasing (free). Thread owns rows
// {tr*4+i, 64+tr*4+i} x cols [tc*TN, tc*TN+TN).
template <int DIN, int DOUT>
__global__ __launch_bounds__(256) void k_gemm(const float* __restrict__ h,
                                              const float* __restrict__ src_norm,
                                              const float* __restrict__ W,
                                              float* __restrict__ out) {
  constexpr int KC   = 32;
  constexpr int ROWS = 128;
  constexpr int TN   = DOUT / 16;
  __shared__ float hT[KC][ROWS];
  __shared__ float Ws[KC][DOUT];

  const int t = threadIdx.x;
  const int rowBase = blockIdx.x * ROWS;
  const int tr = t & 15;
  const int tc = t >> 4;

  float acc[8][TN];
#pragma unroll
  for (int i = 0; i < 8; ++i)
#pragma unroll
    for (int j = 0; j < TN; ++j) acc[i][j] = 0.0f;

  for (int kc = 0; kc < DIN; kc += KC) {
    // stage hT (transposed, norm applied, swizzled writes)
#pragma unroll
    for (int p = 0; p < 4; ++p) {
      int rg = (t >> 3) + 32 * p;
      int ks = (t & 7) * 4;
      float4 v = *reinterpret_cast<const float4*>(&h[(size_t)(rowBase + rg) * DIN + kc + ks]);
      float nrm = src_norm[rowBase + rg];
      hT[ks + 0][rg ^ ((((ks + 0) >> 3) & 3) << 3)] = v.x * nrm;
      hT[ks + 1][rg ^ ((((ks + 1) >> 3) & 3) << 3)] = v.y * nrm;
      hT[ks + 2][rg ^ ((((ks + 2) >> 3) & 3) << 3)] = v.z * nrm;
      hT[ks + 3][rg ^ ((((ks + 3) >> 3) & 3) << 3)] = v.w * nrm;
    }
    // stage Ws
    constexpr int WEL = KC * DOUT;
#pragma unroll
    for (int base = 0; base < WEL; base += 256 * 4) {
      int idx = base + t * 4;
      if (idx < WEL) {
        int kk = idx / DOUT;
        int c  = idx % DOUT;
        *reinterpret_cast<float4*>(&Ws[kk][c]) =
            *reinterpret_cast<const float4*>(&W[(size_t)(kc + kk) * DOUT + c]);
      }
    }
    __syncthreads();
#pragma unroll
    for (int kk = 0; kk < KC; ++kk) {
      const int swz = ((kk >> 3) & 3) << 3;
      float4 a0 = *reinterpret_cast<const float4*>(&hT[kk][(tr * 4) ^ swz]);
      float4 a1 = *reinterpret_cast<const float4*>(&hT[kk][(64 + tr * 4) ^ swz]);
      float bb[TN];
#pragma unroll
      for (int j = 0; j < TN; ++j) bb[j] = Ws[kk][tc * TN + j];
      float av[8] = {a0.x, a0.y, a0.z, a0.w, a1.x, a1.y, a1.z, a1.w};
#pragma unroll
      for (int i = 0; i < 8; ++i)
#pragma unroll
        for (int j = 0; j < TN; ++j) acc[i][j] += av[i] * bb[j];
    }
    __syncthreads();
  }
#pragma unroll
  for (int half = 0; half < 2; ++half) {
#pragma unroll
    for (int i = 0; i < 4; ++i) {
      int row = rowBase + half * 64 + tr * 4 + i;
      float* op = &out[(size_t)row * DOUT + tc * TN];
      if constexpr (TN == 4) {
        float4 v = {acc[half * 4 + i][0], acc[half * 4 + i][1],
                    acc[half * 4 + i][2], acc[half * 4 + i][3]};
        *reinterpret_cast<float4*>(op) = v;
      } else if constexpr (TN == 2) {
        float2 v = {acc[half * 4 + i][0], acc[half * 4 + i][1]};
        *reinterpret_cast<float2*>(op) = v;
      } else {
        op[0] = acc[half * 4 + i][0];
      }
    }
  }
}

// ---------------- aggregation: float4 gathers, D/4 lanes per node ----------------
template <int D>
__global__ __launch_bounds__(256) void k_agg(const float* __restrict__ hw,
                                             const int* __restrict__ row_start,
                                             const int* __restrict__ csr_src,
                                             const float* __restrict__ dst_norm,
                                             const float* __restrict__ bias,
                                             float* __restrict__ out) {
  constexpr int LPN = D / 4;     // lanes per node
  constexpr int NPW = 64 / LPN;  // nodes per wave
  const int t = threadIdx.x;
  const int lane = t & 63;
  const int wave = t >> 6;
  const int f4  = (lane % LPN) * 4;
  const int sub = lane / LPN;
  const int node = (blockIdx.x * 4 + wave) * NPW + sub;
  const int start = row_start[node];
  const int end   = row_start[node + 1];
  float ax = 0.0f, ay = 0.0f, az = 0.0f, aw = 0.0f;
  int i = start;
  for (; i + 4 <= end; i += 4) {
    int s0 = csr_src[i + 0];
    int s1 = csr_src[i + 1];
    int s2 = csr_src[i + 2];
    int s3 = csr_src[i + 3];
    float4 v0 = *reinterpret_cast<const float4*>(&hw[(size_t)s0 * D + f4]);
    float4 v1 = *reinterpret_cast<const float4*>(&hw[(size_t)s1 * D + f4]);
    float4 v2 = *reinterpret_cast<const float4*>(&hw[(size_t)s2 * D + f4]);
    float4 v3 = *reinterpret_cast<const float4*>(&hw[(size_t)s3 * D + f4]);
    ax += v0.x + v1.x + v2.x + v3.x;
    ay += v0.y + v1.y + v2.y + v3.y;
    az += v0.z + v1.z + v2.z + v3.z;
    aw += v0.w + v1.w + v2.w + v3.w;
  }
  for (; i < end; ++i) {
    float4 v = *reinterpret_cast<const float4*>(&hw[(size_t)csr_src[i] * D + f4]);
    ax += v.x; ay += v.y; az += v.z; aw += v.w;
  }
  float nrm = dst_norm[node];
  float4 b4 = *reinterpret_cast<const float4*>(&bias[f4]);
  float4 r;
  r.x = fmaxf(ax * nrm + b4.x, 0.0f);
  r.y = fmaxf(ay * nrm + b4.y, 0.0f);
  r.z = fmaxf(az * nrm + b4.z, 0.0f);
  r.w = fmaxf(aw * nrm + b4.w, 0.0f);
  *reinterpret_cast<float4*>(&out[(size_t)node * D + f4]) = r;
}

// ---------------- pooling ----------------
__global__ __launch_bounds__(256) void k_pool(const float* __restrict__ h3,
                                              const int* __restrict__ gid,
                                              float* __restrict__ sums,
                                              float* __restrict__ cnt) {
  const int t = threadIdx.x;
  const int f = t & 15;
  const int grp = t >> 4;
  const int base = blockIdx.x * POOL_NPB;
  float acc = 0.0f, c = 0.0f;
  int cur = gid[base + grp];
#pragma unroll 4
  for (int k = 0; k < POOL_NPB / 16; ++k) {
    int node = base + grp + k * 16;
    int g = gid[node];
    float v = h3[(size_t)node * 16 + f];
    if (g != cur) {
      atomicAdd(&sums[cur * 16 + f], acc);
      if (f == 0) atomicAdd(&cnt[cur], c);
      acc = 0.0f; c = 0.0f; cur = g;
    }
    acc += v; c += 1.0f;
  }
  atomicAdd(&sums[cur * 16 + f], acc);
  if (f == 0) atomicAdd(&cnt[cur], c);
}

__global__ __launch_bounds__(128) void k_classify(const float* __restrict__ sums,
                                                  const float* __restrict__ cnt,
                                                  const float* __restrict__ Wc,
                                                  const float* __restrict__ bc,
                                                  float* __restrict__ out) {
  int g = threadIdx.x;
  float c = cnt[g]; if (c < 1.0f) c = 1.0f;
  float acc = 0.0f;
#pragma unroll
  for (int f = 0; f < 16; ++f) acc += (sums[g * 16 + f] / c) * Wc[f];
  out[g] = acc + bc[0];
}

// ---------------- launch ----------------
extern "C" void kernel_launch(void* const* d_in, const int* in_sizes, int n_in,
                              void* d_out, int out_size, void* d_ws, size_t ws_size,
                              hipStream_t stream) {
  const float* features = (const float*)d_in[0];
  const int*   src      = (const int*)d_in[1];
  const int*   dst      = (const int*)d_in[2];
  const int*   gid      = (const int*)d_in[3];
  const float* W0 = (const float*)d_in[4];
  const float* b0 = (const float*)d_in[5];
  const float* W1 = (const float*)d_in[6];
  const float* b1 = (const float*)d_in[7];
  const float* W2 = (const float*)d_in[8];
  const float* b2 = (const float*)d_in[9];
  const float* Wc = (const float*)d_in[10];
  const float* bc = (const float*)d_in[11];
  float* out = (float*)d_out;

  char* w = (char*)d_ws;
  auto alloc = [&](size_t bytes) {
    void* p = (void*)w;
    w += (bytes + 255) & ~(size_t)255;
    return p;
  };
  float* src_norm    = (float*)alloc((size_t)N_NODES * 4);
  float* dst_norm    = (float*)alloc((size_t)N_NODES * 4);
  int*   row_start   = (int*)alloc((size_t)(N_NODES + 1) * 4);
  int*   cursor_d    = (int*)alloc(NB * 4);
  int*   cursor_s    = (int*)alloc(NB * 4);
  int*   bucket_base = (int*)alloc(NB * 4);
  int*   csr_src     = (int*)alloc((size_t)N_EDGES * 4);
  float* buf0        = (float*)alloc((size_t)N_NODES * 64 * 4);
  float* buf1        = (float*)alloc((size_t)N_NODES * 64 * 4);
  float* sums        = (float*)alloc((size_t)N_GRAPHS * 16 * 4);
  float* cnt         = (float*)alloc((size_t)N_GRAPHS * 4);
  unsigned int*   recs_d = (unsigned int*)buf0;
  unsigned short* recs_s = (unsigned short*)buf1;

  hipMemsetAsync(sums, 0, (size_t)(N_GRAPHS * 16 + N_GRAPHS) * 4, stream);

  k_init_buckets<<<1, 256, 0, stream>>>(cursor_d, cursor_s);
  k_bin<<<N_EDGES / (256 * BIN_EPT), 256, 0, stream>>>(src, dst, cursor_d, cursor_s,
                                                       recs_d, recs_s);
  k_outdeg<<<NB, 512, 0, stream>>>(recs_s, cursor_s, src_norm);
  k_bucket_scan<<<1, 256, 0, stream>>>(cursor_d, bucket_base, row_start);
  k_fill2<<<NB, 512, 0, stream>>>(recs_d, cursor_d, bucket_base, row_start,
                                  dst_norm, csr_src);

  // layer 0: 256 -> 64
  k_gemm<256, 64><<<N_NODES / 128, 256, 0, stream>>>(features, src_norm, W0, buf0);
  k_agg<64><<<N_NODES / 16, 256, 0, stream>>>(buf0, row_start, csr_src, dst_norm, b0, buf1);
  // layer 1: 64 -> 32
  k_gemm<64, 32><<<N_NODES / 128, 256, 0, stream>>>(buf1, src_norm, W1, buf0);
  k_agg<32><<<N_NODES / 32, 256, 0, stream>>>(buf0, row_start, csr_src, dst_norm, b1, buf1);
  // layer 2: 32 -> 16
  k_gemm<32, 16><<<N_NODES / 128, 256, 0, stream>>>(buf1, src_norm, W2, buf0);
  k_agg<16><<<N_NODES / 64, 256, 0, stream>>>(buf0, row_start, csr_src, dst_norm, b2, buf1);

  k_pool<<<N_NODES / POOL_NPB, 256, 0, stream>>>(buf1, gid, sums, cnt);
  k_classify<<<1, 128, 0, stream>>>(sums, cnt, Wc, bc, out);
}